// Round 3
// baseline (1663.112 us; speedup 1.0000x reference)
//
#include <hip/hip_runtime.h>

// LIIF local-ensemble upsampling — bf16 MFMA, single shared activation buffer.
// B=4, C=64, H=W=64 -> 256x256. MLP 66->256->256->64, fp32 accumulate.
// WG = 256 threads (4 waves) = 64 queries, 4 corners serially.
// One 32KB LDS buffer holds inp -> h1 -> h2 -> out-tile in sequence (barrier
// separated) => 37.9KB total LDS => 4 WG/CU (16 waves/CU).
// Weights pre-swizzled to bf16 MFMA B-fragments in d_ws (coalesced 16B loads).

typedef __bf16 bf16x8 __attribute__((ext_vector_type(8)));
typedef float  f32x4  __attribute__((ext_vector_type(4)));

#define LDS_SWZ(row, kbyte) ((kbyte) ^ (((row) & 7) << 4))

// ws layout (ushort elements): W1p 48 frag-blocks, W2p 128, W3p 32 (1KB each)
#define WP1_U 0
#define WP2_U (48 * 512)
#define WP3_U (176 * 512)

// ---------------- weight prep: fp32 [K][N] -> bf16 B-fragments ----------------
// frag block layout: [ks][ntile][lane][8]  (lane l: k = ks*32+(l>>4)*8+j, n = nt*16+(l&15))
__global__ __launch_bounds__(64) void prep_weights(
    const float* __restrict__ W1, const float* __restrict__ W2,
    const float* __restrict__ W3, ushort* __restrict__ ws)
{
    const int blk = blockIdx.x;    // 0..207
    const int l   = threadIdx.x;   // 0..63
    const float* W; int Kreal, N, ks, nt; size_t off;
    if (blk < 48)       { W = W1; Kreal = 66;  N = 256; ks = blk >> 4;  nt = blk & 15; off = WP1_U + (size_t)blk * 512; }
    else if (blk < 176) { int b2 = blk - 48;  W = W2; Kreal = 256; N = 256; ks = b2 >> 4; nt = b2 & 15; off = WP2_U + (size_t)b2 * 512; }
    else                { int b3 = blk - 176; W = W3; Kreal = 256; N = 64;  ks = b3 >> 2; nt = b3 & 3;  off = WP3_U + (size_t)b3 * 512; }

    const int n = nt * 16 + (l & 15);
    ushort v[8];
    #pragma unroll
    for (int j = 0; j < 8; ++j) {
        const int k = ks * 32 + ((l >> 4) * 8) + j;
        const float f = (k < Kreal) ? W[(size_t)k * N + n] : 0.0f;
        v[j] = __builtin_bit_cast(ushort, (__bf16)f);
    }
    *(uint4*)(ws + off + (size_t)l * 8) = *(const uint4*)v;
}

// ---------------- K-loop: LDS(src) x Wp -> acc (no epilogue) ----------------
template<int KSTEPS, int SRC_STRIDE>
__device__ inline void compute_layer(const char* __restrict__ src,
                                     const ushort* __restrict__ wp,
                                     int lane, int wv, f32x4 (&acc)[4][4])
{
    const int lrow = lane & 15;
    const int lk   = lane >> 4;
    #pragma unroll
    for (int mt = 0; mt < 4; ++mt)
        #pragma unroll
        for (int nt = 0; nt < 4; ++nt)
            acc[mt][nt] = (f32x4){0.f, 0.f, 0.f, 0.f};

    #pragma unroll
    for (int ks = 0; ks < KSTEPS; ++ks) {
        bf16x8 a[4], bb[4];
        #pragma unroll
        for (int mt = 0; mt < 4; ++mt) {
            const int row   = mt * 16 + lrow;
            const int kbyte = ks * 64 + lk * 16;
            a[mt] = *(const bf16x8*)(src + row * SRC_STRIDE + LDS_SWZ(row, kbyte));
        }
        #pragma unroll
        for (int nt = 0; nt < 4; ++nt) {
            const int ntg = wv * 4 + nt;
            bb[nt] = *(const bf16x8*)(wp + (((size_t)(ks * 16 + ntg)) << 9) + (lane << 3));
        }
        #pragma unroll
        for (int mt = 0; mt < 4; ++mt)
            #pragma unroll
            for (int nt = 0; nt < 4; ++nt)
                acc[mt][nt] = __builtin_amdgcn_mfma_f32_16x16x32_bf16(a[mt], bb[nt], acc[mt][nt], 0, 0, 0);
    }
}

// ---------------- epilogue: relu(acc+bias) -> bf16 LDS tile (stride 512B) ----------------
__device__ inline void store_hidden(char* __restrict__ dst, const f32x4 (&acc)[4][4],
                                    const float* __restrict__ bias, int lane, int wv)
{
    const int lrow = lane & 15;
    const int lk   = lane >> 4;
    #pragma unroll
    for (int nt = 0; nt < 4; ++nt) {
        const int n  = wv * 64 + nt * 16 + lrow;
        const float bs = bias[n];
        const int kbyte = 2 * n;
        #pragma unroll
        for (int mt = 0; mt < 4; ++mt) {
            #pragma unroll
            for (int r = 0; r < 4; ++r) {
                const int row = mt * 16 + lk * 4 + r;
                const float v = fmaxf(acc[mt][nt][r] + bs, 0.0f);
                *(ushort*)(dst + row * 512 + LDS_SWZ(row, kbyte)) = __builtin_bit_cast(ushort, (__bf16)v);
            }
        }
    }
}

// ---------------- main kernel ----------------
__global__ __launch_bounds__(256, 4) void liif_mfma_kernel(
    const float* __restrict__ x,
    const float* __restrict__ b1f, const float* __restrict__ b2f, const float* __restrict__ b3f,
    const ushort* __restrict__ ws, float* __restrict__ out)
{
    __shared__ char buf[32 * 1024];    // inp(16K,str256) -> h1(32K,str512) -> h2 -> out f32 tile(16K,str256)
    __shared__ int   s_iy[4][64], s_ix[4][64];
    __shared__ float s_rely[4][64], s_relx[4][64], s_w[4][64];

    const int tid  = threadIdx.x;
    const int lane = tid & 63;
    const int wv   = tid >> 6;          // 0..3
    const int lrow = lane & 15;
    const int lk   = lane >> 4;
    const int bq   = blockIdx.x;        // 0..4095
    const int b    = bq >> 10;
    const int q0   = (bq & 1023) << 6;  // 64 queries per WG

    // ---- per-query geometry, all 4 corners ----
    if (tid < 64) {
        const int q  = q0 + tid;
        const int yq = q >> 8, xq = q & 255;
        const float cy  = -1.0f + (2.0f * yq + 1.0f) / 256.0f;
        const float cx  = -1.0f + (2.0f * xq + 1.0f) / 256.0f;
        const float lim = 1.0f - 1e-6f;
        float area[4];
        #pragma unroll
        for (int c = 0; c < 4; ++c) {
            const float vx = (c & 2) ? 1.0f : -1.0f;
            const float vy = (c & 1) ? 1.0f : -1.0f;
            float sy = cy + vx * (1.0f / 64.0f) + 1e-6f;
            float sx = cx + vy * (1.0f / 64.0f) + 1e-6f;
            sy = fminf(fmaxf(sy, -lim), lim);
            sx = fminf(fmaxf(sx, -lim), lim);
            int iy = (int)rintf(((sy + 1.0f) * 64.0f - 1.0f) * 0.5f);
            int ix = (int)rintf(((sx + 1.0f) * 64.0f - 1.0f) * 0.5f);
            iy = min(max(iy, 0), 63);
            ix = min(max(ix, 0), 63);
            const float fy = -1.0f + (2.0f * iy + 1.0f) / 64.0f;
            const float fx = -1.0f + (2.0f * ix + 1.0f) / 64.0f;
            const float ry = (cy - fy) * 64.0f;
            const float rx = (cx - fx) * 64.0f;
            s_iy[c][tid] = iy;   s_ix[c][tid] = ix;
            s_rely[c][tid] = ry; s_relx[c][tid] = rx;
            area[c] = fabsf(ry * rx) + 1e-9f;
        }
        const float tot = area[0] + area[1] + area[2] + area[3];
        #pragma unroll
        for (int c = 0; c < 4; ++c) s_w[c][tid] = area[3 - c] / tot;   // 0<->3, 1<->2 swap
    }
    __syncthreads();

    float oacc[4][4];
    #pragma unroll
    for (int mt = 0; mt < 4; ++mt)
        #pragma unroll
        for (int r = 0; r < 4; ++r) oacc[mt][r] = 0.0f;

    f32x4 acc[4][4];

    for (int c = 0; c < 4; ++c) {
        // ---- stage inp tile: rows 0..63, stride 256B, swizzled, K padded to 96 ----
        {
            const int r = tid >> 2, p = tid & 3;
            const int iy = s_iy[c][r], ix = s_ix[c][r];
            const float* xb = x + (((size_t)b * 64) * 64 + iy) * 64 + ix;
            #pragma unroll
            for (int half = 0; half < 2; ++half) {
                ushort tmp[8];
                #pragma unroll
                for (int j = 0; j < 8; ++j) {
                    const float f = xb[(size_t)(p * 16 + half * 8 + j) * 4096];
                    tmp[j] = __builtin_bit_cast(ushort, (__bf16)f);
                }
                const int kbyte = p * 32 + half * 16;
                *(uint4*)(buf + r * 256 + LDS_SWZ(r, kbyte)) = *(const uint4*)tmp;
            }
            ushort pad[8] = {0, 0, 0, 0, 0, 0, 0, 0};
            if (p == 0) {
                pad[0] = __builtin_bit_cast(ushort, (__bf16)s_rely[c][r]);
                pad[1] = __builtin_bit_cast(ushort, (__bf16)s_relx[c][r]);
            }
            const int kbyte = 128 + p * 16;
            *(uint4*)(buf + r * 256 + LDS_SWZ(r, kbyte)) = *(const uint4*)pad;
        }
        __syncthreads();

        // ---- layer 1: inp -> h1 (in place after barrier) ----
        compute_layer<3, 256>(buf, ws + WP1_U, lane, wv, acc);
        __syncthreads();
        store_hidden(buf, acc, b1f, lane, wv);
        __syncthreads();

        // ---- layer 2: h1 -> h2 (in place) ----
        compute_layer<8, 512>(buf, ws + WP2_U, lane, wv, acc);
        __syncthreads();
        store_hidden(buf, acc, b2f, lane, wv);
        __syncthreads();

        // ---- layer 3: h2 -> weighted out accumulation (N=16 per wave) ----
        {
            f32x4 acc3[4];
            #pragma unroll
            for (int mt = 0; mt < 4; ++mt) acc3[mt] = (f32x4){0.f, 0.f, 0.f, 0.f};
            #pragma unroll
            for (int ks = 0; ks < 8; ++ks) {
                bf16x8 a[4];
                #pragma unroll
                for (int mt = 0; mt < 4; ++mt) {
                    const int row   = mt * 16 + lrow;
                    const int kbyte = ks * 64 + lk * 16;
                    a[mt] = *(const bf16x8*)(buf + row * 512 + LDS_SWZ(row, kbyte));
                }
                const bf16x8 bb = *(const bf16x8*)(ws + WP3_U + (((size_t)(ks * 4 + wv)) << 9) + (lane << 3));
                #pragma unroll
                for (int mt = 0; mt < 4; ++mt)
                    acc3[mt] = __builtin_amdgcn_mfma_f32_16x16x32_bf16(a[mt], bb, acc3[mt], 0, 0, 0);
            }
            const float bs = b3f[wv * 16 + lrow];
            #pragma unroll
            for (int mt = 0; mt < 4; ++mt) {
                #pragma unroll
                for (int r = 0; r < 4; ++r) {
                    const int row = mt * 16 + lk * 4 + r;
                    oacc[mt][r] += (acc3[mt][r] + bs) * s_w[c][row];
                }
            }
        }
        __syncthreads();   // all L3 reads done before next corner's stage / out-stage
    }

    // ---- stage out tile in LDS (f32, rows=query, stride 256B, swizzled) ----
    #pragma unroll
    for (int mt = 0; mt < 4; ++mt) {
        #pragma unroll
        for (int r = 0; r < 4; ++r) {
            const int row = mt * 16 + lk * 4 + r;
            const int cb  = (wv * 16 + lrow) * 4;
            *(float*)(buf + row * 256 + LDS_SWZ(row, cb)) = oacc[mt][r];
        }
    }
    __syncthreads();

    // ---- fully-coalesced store: 4 threads x dwordx4 x 4 = 256B per query row ----
    {
        const int row = tid >> 2, seg = tid & 3;
        const size_t obase = ((size_t)b * 65536 + q0 + row) * 64 + seg * 16;
        #pragma unroll
        for (int j = 0; j < 4; ++j) {
            const int kb = seg * 64 + j * 16;
            uint4 v = *(const uint4*)(buf + row * 256 + LDS_SWZ(row, kb));
            *(uint4*)(out + obase + j * 4) = v;
        }
    }
}

extern "C" void kernel_launch(void* const* d_in, const int* in_sizes, int n_in,
                              void* d_out, int out_size, void* d_ws, size_t ws_size,
                              hipStream_t stream) {
    const float* x  = (const float*)d_in[0];
    const float* W1 = (const float*)d_in[1];
    const float* b1 = (const float*)d_in[2];
    const float* W2 = (const float*)d_in[3];
    const float* b2 = (const float*)d_in[4];
    const float* W3 = (const float*)d_in[5];
    const float* b3 = (const float*)d_in[6];
    float* out = (float*)d_out;
    ushort* wp = (ushort*)d_ws;

    prep_weights<<<208, 64, 0, stream>>>(W1, W2, W3, wp);
    liif_mfma_kernel<<<4096, 256, 0, stream>>>(x, b1, b2, b3, wp, out);
}

// Round 4
// 500.858 us; speedup vs baseline: 3.3205x; 3.3205x over previous
//
#include <hip/hip_runtime.h>

// LIIF local-ensemble upsampling — bf16 MFMA, corner-parallel.
// WG = 512 threads (8 waves) = 32 queries x 4 corners = M=128 rows through
// the MLP 66->256->256->64 ONCE (corners folded into M). fp32 accumulate.
// Single 64KB LDS buffer reused in-place: inp(32K) -> h1(64K) -> h2(64K) ->
// pred f32(32K), barrier-separated. 8 barriers/block. 2 WG/CU (16 waves).
// Weights pre-swizzled to bf16 MFMA B-fragments in d_ws.

typedef __bf16 bf16x8 __attribute__((ext_vector_type(8)));
typedef float  f32x4  __attribute__((ext_vector_type(4)));

#define LDS_SWZ(row, kbyte) ((kbyte) ^ (((row) & 7) << 4))

// ws layout (ushort elements): W1p 48 frag-blocks, W2p 128, W3p 32 (1KB each)
#define WP1_U 0
#define WP2_U (48 * 512)
#define WP3_U (176 * 512)

// ---------------- weight prep: fp32 [K][N] -> bf16 B-fragments ----------------
// frag block: [ks][ntile][lane][8]  (lane l: k = ks*32+(l>>4)*8+j, n = nt*16+(l&15))
__global__ __launch_bounds__(64) void prep_weights(
    const float* __restrict__ W1, const float* __restrict__ W2,
    const float* __restrict__ W3, ushort* __restrict__ ws)
{
    const int blk = blockIdx.x;    // 0..207
    const int l   = threadIdx.x;   // 0..63
    const float* W; int Kreal, N, ks, nt; size_t off;
    if (blk < 48)       { W = W1; Kreal = 66;  N = 256; ks = blk >> 4;  nt = blk & 15; off = WP1_U + (size_t)blk * 512; }
    else if (blk < 176) { int b2 = blk - 48;  W = W2; Kreal = 256; N = 256; ks = b2 >> 4; nt = b2 & 15; off = WP2_U + (size_t)b2 * 512; }
    else                { int b3 = blk - 176; W = W3; Kreal = 256; N = 64;  ks = b3 >> 2; nt = b3 & 3;  off = WP3_U + (size_t)b3 * 512; }

    const int n = nt * 16 + (l & 15);
    ushort v[8];
    #pragma unroll
    for (int j = 0; j < 8; ++j) {
        const int k = ks * 32 + ((l >> 4) * 8) + j;
        const float f = (k < Kreal) ? W[(size_t)k * N + n] : 0.0f;
        v[j] = __builtin_bit_cast(ushort, (__bf16)f);
    }
    *(uint4*)(ws + off + (size_t)l * 8) = *(const uint4*)v;
}

// ---------------- K-loop: LDS(src) x Wp -> acc ----------------
// wave covers rows [mbase, mbase+64), cols [(nbase_t)*16, +64)
template<int KSTEPS, int SRC_STRIDE>
__device__ inline void compute_layer(const char* __restrict__ src,
                                     const ushort* __restrict__ wp,
                                     int lane, int mbase, int nbase_t, f32x4 (&acc)[4][4])
{
    const int lrow = lane & 15;
    const int lk   = lane >> 4;
    #pragma unroll
    for (int mt = 0; mt < 4; ++mt)
        #pragma unroll
        for (int nt = 0; nt < 4; ++nt)
            acc[mt][nt] = (f32x4){0.f, 0.f, 0.f, 0.f};

    #pragma unroll
    for (int ks = 0; ks < KSTEPS; ++ks) {
        bf16x8 a[4], bb[4];
        #pragma unroll
        for (int mt = 0; mt < 4; ++mt) {
            const int row   = mbase + mt * 16 + lrow;
            const int kbyte = ks * 64 + lk * 16;
            a[mt] = *(const bf16x8*)(src + row * SRC_STRIDE + LDS_SWZ(row, kbyte));
        }
        #pragma unroll
        for (int nt = 0; nt < 4; ++nt) {
            const int ntg = nbase_t + nt;
            bb[nt] = *(const bf16x8*)(wp + (((size_t)(ks * 16 + ntg)) << 9) + (lane << 3));
        }
        #pragma unroll
        for (int mt = 0; mt < 4; ++mt)
            #pragma unroll
            for (int nt = 0; nt < 4; ++nt)
                acc[mt][nt] = __builtin_amdgcn_mfma_f32_16x16x32_bf16(a[mt], bb[nt], acc[mt][nt], 0, 0, 0);
    }
}

// ---------------- epilogue: relu(acc+bias) -> bf16 LDS tile (stride 512B) ----------------
__device__ inline void store_hidden(char* __restrict__ dst, const f32x4 (&acc)[4][4],
                                    const float* __restrict__ bias,
                                    int lane, int mbase, int nbase_t)
{
    const int lrow = lane & 15;
    const int lk   = lane >> 4;
    #pragma unroll
    for (int nt = 0; nt < 4; ++nt) {
        const int n  = (nbase_t + nt) * 16 + lrow;
        const float bs = bias[n];
        const int kbyte = 2 * n;
        #pragma unroll
        for (int mt = 0; mt < 4; ++mt) {
            #pragma unroll
            for (int r = 0; r < 4; ++r) {
                const int row = mbase + mt * 16 + lk * 4 + r;
                const float v = fmaxf(acc[mt][nt][r] + bs, 0.0f);
                *(ushort*)(dst + row * 512 + LDS_SWZ(row, kbyte)) = __builtin_bit_cast(ushort, (__bf16)v);
            }
        }
    }
}

// ---------------- main kernel ----------------
__global__ __launch_bounds__(512, 4) void liif_mfma2_kernel(
    const float* __restrict__ x,
    const float* __restrict__ b1f, const float* __restrict__ b2f, const float* __restrict__ b3f,
    const ushort* __restrict__ ws, float* __restrict__ out)
{
    __shared__ char buf[64 * 1024];   // inp(32K,str256) -> h1/h2(64K,str512) -> pred f32(32K,str256)
    __shared__ int   s_iy[4][32], s_ix[4][32];
    __shared__ float s_rely[4][32], s_relx[4][32], s_w[4][32];

    const int tid  = threadIdx.x;
    const int lane = tid & 63;
    const int wv   = tid >> 6;            // 0..7
    const int lrow = lane & 15;
    const int lk   = lane >> 4;

    const int bid0 = blockIdx.x;          // 0..8191
    const int bid  = (bid0 & 7) * 1024 + (bid0 >> 3);   // XCD-contiguous remap (bijective)
    const int b    = bid >> 11;           // batch 0..3
    const int q0   = (bid & 2047) << 5;   // 32 queries per WG

    // wave tiling: M=128 rows, N=256 cols -> wave (mh, nq)
    const int mbase   = (wv >> 2) * 64;   // 0 or 64
    const int nbase_t = (wv & 3) * 4;     // nt tile base (x16 cols)

    // ---- per-query geometry, all 4 corners ----
    if (tid < 32) {
        const int q  = q0 + tid;
        const int yq = q >> 8, xq = q & 255;
        const float cy  = -1.0f + (2.0f * yq + 1.0f) / 256.0f;
        const float cx  = -1.0f + (2.0f * xq + 1.0f) / 256.0f;
        const float lim = 1.0f - 1e-6f;
        float area[4];
        #pragma unroll
        for (int c = 0; c < 4; ++c) {
            const float vx = (c & 2) ? 1.0f : -1.0f;
            const float vy = (c & 1) ? 1.0f : -1.0f;
            float sy = cy + vx * (1.0f / 64.0f) + 1e-6f;
            float sx = cx + vy * (1.0f / 64.0f) + 1e-6f;
            sy = fminf(fmaxf(sy, -lim), lim);
            sx = fminf(fmaxf(sx, -lim), lim);
            int iy = (int)rintf(((sy + 1.0f) * 64.0f - 1.0f) * 0.5f);
            int ix = (int)rintf(((sx + 1.0f) * 64.0f - 1.0f) * 0.5f);
            iy = min(max(iy, 0), 63);
            ix = min(max(ix, 0), 63);
            const float fy = -1.0f + (2.0f * iy + 1.0f) / 64.0f;
            const float fx = -1.0f + (2.0f * ix + 1.0f) / 64.0f;
            const float ry = (cy - fy) * 64.0f;
            const float rx = (cx - fx) * 64.0f;
            s_iy[c][tid] = iy;   s_ix[c][tid] = ix;
            s_rely[c][tid] = ry; s_relx[c][tid] = rx;
            area[c] = fabsf(ry * rx) + 1e-9f;
        }
        const float tot = area[0] + area[1] + area[2] + area[3];
        #pragma unroll
        for (int c = 0; c < 4; ++c) s_w[c][tid] = area[3 - c] / tot;   // 0<->3, 1<->2 swap
    }
    __syncthreads();

    // ---- stage inp tile: row = c*32+q, 128 rows, stride 256B, swizzled, K->96 ----
    {
        const int r = tid >> 2, p = tid & 3;           // 4 threads per row
        const int c = r >> 5, q = r & 31;
        const int iy = s_iy[c][q], ix = s_ix[c][q];
        const float* xb = x + (size_t)b * 262144 + iy * 64 + ix;
        #pragma unroll
        for (int half = 0; half < 2; ++half) {
            ushort tmp[8];
            #pragma unroll
            for (int j = 0; j < 8; ++j) {
                const float f = xb[(size_t)(p * 16 + half * 8 + j) * 4096];
                tmp[j] = __builtin_bit_cast(ushort, (__bf16)f);
            }
            const int kbyte = p * 32 + half * 16;
            *(uint4*)(buf + r * 256 + LDS_SWZ(r, kbyte)) = *(const uint4*)tmp;
        }
        ushort pad[8] = {0, 0, 0, 0, 0, 0, 0, 0};
        if (p == 0) {
            pad[0] = __builtin_bit_cast(ushort, (__bf16)s_rely[c][q]);
            pad[1] = __builtin_bit_cast(ushort, (__bf16)s_relx[c][q]);
        }
        const int kbyte = 128 + p * 16;
        *(uint4*)(buf + r * 256 + LDS_SWZ(r, kbyte)) = *(const uint4*)pad;
    }
    __syncthreads();

    f32x4 acc[4][4];

    // ---- layer 1: inp -> h1 (in place, barrier-separated) ----
    compute_layer<3, 256>(buf, ws + WP1_U, lane, mbase, nbase_t, acc);
    __syncthreads();
    store_hidden(buf, acc, b1f, lane, mbase, nbase_t);
    __syncthreads();

    // ---- layer 2: h1 -> h2 (in place) ----
    compute_layer<8, 512>(buf, ws + WP2_U, lane, mbase, nbase_t, acc);
    __syncthreads();
    store_hidden(buf, acc, b2f, lane, mbase, nbase_t);
    __syncthreads();

    // ---- layer 3: h2 -> pred (weighted, f32, stride 256B) ----
    {
        const int nt3    = wv & 3;           // one 16-col tile of N=64
        const int mbase3 = (wv >> 2) * 64;
        f32x4 acc3[4];
        #pragma unroll
        for (int mt = 0; mt < 4; ++mt) acc3[mt] = (f32x4){0.f, 0.f, 0.f, 0.f};
        #pragma unroll
        for (int ks = 0; ks < 8; ++ks) {
            bf16x8 a[4];
            #pragma unroll
            for (int mt = 0; mt < 4; ++mt) {
                const int row   = mbase3 + mt * 16 + lrow;
                const int kbyte = ks * 64 + lk * 16;
                a[mt] = *(const bf16x8*)(buf + row * 512 + LDS_SWZ(row, kbyte));
            }
            const bf16x8 bb = *(const bf16x8*)(ws + WP3_U + (((size_t)(ks * 4 + nt3)) << 9) + (lane << 3));
            #pragma unroll
            for (int mt = 0; mt < 4; ++mt)
                acc3[mt] = __builtin_amdgcn_mfma_f32_16x16x32_bf16(a[mt], bb, acc3[mt], 0, 0, 0);
        }
        __syncthreads();   // all h2 reads done before pred overwrites buf
        const float bs = b3f[nt3 * 16 + lrow];
        #pragma unroll
        for (int mt = 0; mt < 4; ++mt) {
            #pragma unroll
            for (int r = 0; r < 4; ++r) {
                const int row = mbase3 + mt * 16 + lk * 4 + r;    // = c*32 + q
                const float wgt = s_w[row >> 5][row & 31];
                const int cb = (nt3 * 16 + lrow) * 4;
                *(float*)(buf + row * 256 + LDS_SWZ(row, cb)) = (acc3[mt][r] + bs) * wgt;
            }
        }
    }
    __syncthreads();

    // ---- final: sum 4 corner rows, fully-coalesced dwordx4 store ----
    {
        const int q  = tid >> 4;          // 0..31
        const int ch = (tid & 15) * 4;    // 0..60
        f32x4 sum = (f32x4){0.f, 0.f, 0.f, 0.f};
        #pragma unroll
        for (int c = 0; c < 4; ++c) {
            const int row = c * 32 + q;
            const f32x4 v = *(const f32x4*)(buf + row * 256 + LDS_SWZ(row, ch * 4));
            sum += v;
        }
        *(f32x4*)(out + ((size_t)b * 65536 + q0 + q) * 64 + ch) = sum;
    }
}

extern "C" void kernel_launch(void* const* d_in, const int* in_sizes, int n_in,
                              void* d_out, int out_size, void* d_ws, size_t ws_size,
                              hipStream_t stream) {
    const float* x  = (const float*)d_in[0];
    const float* W1 = (const float*)d_in[1];
    const float* b1 = (const float*)d_in[2];
    const float* W2 = (const float*)d_in[3];
    const float* b2 = (const float*)d_in[4];
    const float* W3 = (const float*)d_in[5];
    const float* b3 = (const float*)d_in[6];
    float* out = (float*)d_out;
    ushort* wp = (ushort*)d_ws;

    prep_weights<<<208, 64, 0, stream>>>(W1, W2, W3, wp);
    liif_mfma2_kernel<<<8192, 512, 0, stream>>>(x, b1, b2, b3, wp, out);
}

// Round 5
// 460.784 us; speedup vs baseline: 3.6093x; 1.0870x over previous
//
#include <hip/hip_runtime.h>

// LIIF local-ensemble upsampling — bf16 MFMA, corner-parallel, low-VGPR K-loop.
// WG = 512 threads (8 waves) = 32 queries x 4 corners = M=128 rows through
// MLP 66->256->256->64 once. fp32 accumulate in AGPRs, bias in acc-init.
// Single 64KB LDS buffer in-place: inp(32K) -> h1(64K) -> h2(64K) -> pred(32K).
// K-loop: bb[4] per ks, single-A sequential mt (arch-VGPR live set < 64).

typedef __bf16 bf16x8 __attribute__((ext_vector_type(8)));
typedef float  f32x4  __attribute__((ext_vector_type(4)));

#define LDS_SWZ(row, kbyte) ((kbyte) ^ (((row) & 7) << 4))

// ws layout (ushort elements): W1p 48 frag-blocks, W2p 128, W3p 32 (1KB each)
#define WP1_U 0
#define WP2_U (48 * 512)
#define WP3_U (176 * 512)

// ---------------- weight prep: fp32 [K][N] -> bf16 B-fragments ----------------
// frag block: [ks][ntile][lane][8]  (lane l: k = ks*32+(l>>4)*8+j, n = nt*16+(l&15))
__global__ __launch_bounds__(64) void prep_weights(
    const float* __restrict__ W1, const float* __restrict__ W2,
    const float* __restrict__ W3, ushort* __restrict__ ws)
{
    const int blk = blockIdx.x;    // 0..207
    const int l   = threadIdx.x;   // 0..63
    const float* W; int Kreal, N, ks, nt; size_t off;
    if (blk < 48)       { W = W1; Kreal = 66;  N = 256; ks = blk >> 4;  nt = blk & 15; off = WP1_U + (size_t)blk * 512; }
    else if (blk < 176) { int b2 = blk - 48;  W = W2; Kreal = 256; N = 256; ks = b2 >> 4; nt = b2 & 15; off = WP2_U + (size_t)b2 * 512; }
    else                { int b3 = blk - 176; W = W3; Kreal = 256; N = 64;  ks = b3 >> 2; nt = b3 & 3;  off = WP3_U + (size_t)b3 * 512; }

    const int n = nt * 16 + (l & 15);
    ushort v[8];
    #pragma unroll
    for (int j = 0; j < 8; ++j) {
        const int k = ks * 32 + ((l >> 4) * 8) + j;
        const float f = (k < Kreal) ? W[(size_t)k * N + n] : 0.0f;
        v[j] = __builtin_bit_cast(ushort, (__bf16)f);
    }
    *(uint4*)(ws + off + (size_t)l * 8) = *(const uint4*)v;
}

// ---------------- K-loop: LDS(src) x Wp + bias -> acc (AGPR) ----------------
template<int KSTEPS, int SRC_STRIDE>
__device__ inline void compute_layer(const char* __restrict__ src,
                                     const ushort* __restrict__ wp,
                                     const float* __restrict__ bias,
                                     int lane, int mbase, int nbase_t, f32x4 (&acc)[4][4])
{
    const int lrow = lane & 15;
    const int lk   = lane >> 4;
    #pragma unroll
    for (int nt = 0; nt < 4; ++nt) {
        const float bs = bias[(nbase_t + nt) * 16 + lrow];
        #pragma unroll
        for (int mt = 0; mt < 4; ++mt)
            acc[mt][nt] = (f32x4){bs, bs, bs, bs};
    }

    const ushort* wpl = wp + (((size_t)nbase_t) << 9) + (lane << 3);
    #pragma unroll 1
    for (int ks = 0; ks < KSTEPS; ++ks) {
        bf16x8 bb[4];
        #pragma unroll
        for (int nt = 0; nt < 4; ++nt)
            bb[nt] = *(const bf16x8*)(wpl + (((size_t)(ks * 16 + nt)) << 9));
        #pragma unroll
        for (int mt = 0; mt < 4; ++mt) {
            const int row   = mbase + mt * 16 + lrow;
            const int kbyte = ks * 64 + lk * 16;
            const bf16x8 a = *(const bf16x8*)(src + row * SRC_STRIDE + LDS_SWZ(row, kbyte));
            __builtin_amdgcn_s_setprio(1);
            #pragma unroll
            for (int nt = 0; nt < 4; ++nt)
                acc[mt][nt] = __builtin_amdgcn_mfma_f32_16x16x32_bf16(a, bb[nt], acc[mt][nt], 0, 0, 0);
            __builtin_amdgcn_s_setprio(0);
        }
    }
}

// ---------------- epilogue: relu(acc) -> bf16 LDS tile (stride 512B) ----------------
__device__ inline void store_hidden(char* __restrict__ dst, const f32x4 (&acc)[4][4],
                                    int lane, int mbase, int nbase_t)
{
    const int lrow = lane & 15;
    const int lk   = lane >> 4;
    #pragma unroll
    for (int nt = 0; nt < 4; ++nt) {
        const int n  = (nbase_t + nt) * 16 + lrow;
        const int kbyte = 2 * n;
        #pragma unroll
        for (int mt = 0; mt < 4; ++mt) {
            #pragma unroll
            for (int r = 0; r < 4; ++r) {
                const int row = mbase + mt * 16 + lk * 4 + r;
                const float v = fmaxf(acc[mt][nt][r], 0.0f);
                *(ushort*)(dst + row * 512 + LDS_SWZ(row, kbyte)) = __builtin_bit_cast(ushort, (__bf16)v);
            }
        }
    }
}

// ---------------- main kernel ----------------
__global__ __launch_bounds__(512, 4) void liif_mfma3_kernel(
    const float* __restrict__ x,
    const float* __restrict__ b1f, const float* __restrict__ b2f, const float* __restrict__ b3f,
    const ushort* __restrict__ ws, float* __restrict__ out)
{
    __shared__ char buf[64 * 1024];   // inp(32K,str256) -> h1/h2(64K,str512) -> pred f32(32K,str256)
    __shared__ int   s_iy[4][32], s_ix[4][32];
    __shared__ float s_rely[4][32], s_relx[4][32], s_w[4][32];

    const int tid  = threadIdx.x;
    const int lane = tid & 63;
    const int wv   = tid >> 6;            // 0..7
    const int lrow = lane & 15;
    const int lk   = lane >> 4;

    const int bid0 = blockIdx.x;          // 0..8191
    const int bid  = (bid0 & 7) * 1024 + (bid0 >> 3);   // XCD-contiguous remap (bijective)
    const int b    = bid >> 11;           // batch 0..3
    const int q0   = (bid & 2047) << 5;   // 32 queries per WG

    const int mbase   = (wv >> 2) * 64;   // 0 or 64
    const int nbase_t = (wv & 3) * 4;     // nt tile base (x16 cols)

    // ---- per-query geometry, all 4 corners ----
    if (tid < 32) {
        const int q  = q0 + tid;
        const int yq = q >> 8, xq = q & 255;
        const float cy  = -1.0f + (2.0f * yq + 1.0f) / 256.0f;
        const float cx  = -1.0f + (2.0f * xq + 1.0f) / 256.0f;
        const float lim = 1.0f - 1e-6f;
        float area[4];
        #pragma unroll
        for (int c = 0; c < 4; ++c) {
            const float vx = (c & 2) ? 1.0f : -1.0f;
            const float vy = (c & 1) ? 1.0f : -1.0f;
            float sy = cy + vx * (1.0f / 64.0f) + 1e-6f;
            float sx = cx + vy * (1.0f / 64.0f) + 1e-6f;
            sy = fminf(fmaxf(sy, -lim), lim);
            sx = fminf(fmaxf(sx, -lim), lim);
            int iy = (int)rintf(((sy + 1.0f) * 64.0f - 1.0f) * 0.5f);
            int ix = (int)rintf(((sx + 1.0f) * 64.0f - 1.0f) * 0.5f);
            iy = min(max(iy, 0), 63);
            ix = min(max(ix, 0), 63);
            const float fy = -1.0f + (2.0f * iy + 1.0f) / 64.0f;
            const float fx = -1.0f + (2.0f * ix + 1.0f) / 64.0f;
            const float ry = (cy - fy) * 64.0f;
            const float rx = (cx - fx) * 64.0f;
            s_iy[c][tid] = iy;   s_ix[c][tid] = ix;
            s_rely[c][tid] = ry; s_relx[c][tid] = rx;
            area[c] = fabsf(ry * rx) + 1e-9f;
        }
        const float tot = area[0] + area[1] + area[2] + area[3];
        #pragma unroll
        for (int c = 0; c < 4; ++c) s_w[c][tid] = area[3 - c] / tot;   // 0<->3, 1<->2 swap
    }
    __syncthreads();

    // ---- stage inp tile: row = c*32+q, 128 rows, stride 256B, swizzled, K->96 ----
    {
        const int r = tid >> 2, p = tid & 3;           // 4 threads per row
        const int c = r >> 5, q = r & 31;
        const int iy = s_iy[c][q], ix = s_ix[c][q];
        const float* xb = x + (size_t)b * 262144 + iy * 64 + ix;
        #pragma unroll
        for (int half = 0; half < 2; ++half) {
            ushort tmp[8];
            #pragma unroll
            for (int j = 0; j < 8; ++j) {
                const float f = xb[(size_t)(p * 16 + half * 8 + j) * 4096];
                tmp[j] = __builtin_bit_cast(ushort, (__bf16)f);
            }
            const int kbyte = p * 32 + half * 16;
            *(uint4*)(buf + r * 256 + LDS_SWZ(r, kbyte)) = *(const uint4*)tmp;
        }
        ushort pad[8] = {0, 0, 0, 0, 0, 0, 0, 0};
        if (p == 0) {
            pad[0] = __builtin_bit_cast(ushort, (__bf16)s_rely[c][q]);
            pad[1] = __builtin_bit_cast(ushort, (__bf16)s_relx[c][q]);
        }
        const int kbyte = 128 + p * 16;
        *(uint4*)(buf + r * 256 + LDS_SWZ(r, kbyte)) = *(const uint4*)pad;
    }
    __syncthreads();

    f32x4 acc[4][4];

    // ---- layer 1: inp -> h1 (in place, barrier-separated) ----
    compute_layer<3, 256>(buf, ws + WP1_U, b1f, lane, mbase, nbase_t, acc);
    __syncthreads();
    store_hidden(buf, acc, lane, mbase, nbase_t);
    __syncthreads();

    // ---- layer 2: h1 -> h2 (in place) ----
    compute_layer<8, 512>(buf, ws + WP2_U, b2f, lane, mbase, nbase_t, acc);
    __syncthreads();
    store_hidden(buf, acc, lane, mbase, nbase_t);
    __syncthreads();

    // ---- layer 3: h2 -> pred (weighted, f32, stride 256B) ----
    {
        const int nt3    = wv & 3;           // one 16-col tile of N=64
        const int mbase3 = (wv >> 2) * 64;
        const float bs = b3f[nt3 * 16 + lrow];
        f32x4 acc3[4];
        #pragma unroll
        for (int mt = 0; mt < 4; ++mt) acc3[mt] = (f32x4){bs, bs, bs, bs};

        const ushort* wp3 = ws + WP3_U + (lane << 3);
        #pragma unroll 1
        for (int ks = 0; ks < 8; ++ks) {
            const bf16x8 bb = *(const bf16x8*)(wp3 + (((size_t)(ks * 4 + nt3)) << 9));
            #pragma unroll
            for (int mt = 0; mt < 4; ++mt) {
                const int row   = mbase3 + mt * 16 + lrow;
                const int kbyte = ks * 64 + lk * 16;
                const bf16x8 a = *(const bf16x8*)(buf + row * 512 + LDS_SWZ(row, kbyte));
                __builtin_amdgcn_s_setprio(1);
                acc3[mt] = __builtin_amdgcn_mfma_f32_16x16x32_bf16(a, bb, acc3[mt], 0, 0, 0);
                __builtin_amdgcn_s_setprio(0);
            }
        }
        __syncthreads();   // all h2 reads done before pred overwrites buf
        #pragma unroll
        for (int mt = 0; mt < 4; ++mt) {
            #pragma unroll
            for (int r = 0; r < 4; ++r) {
                const int row = mbase3 + mt * 16 + lk * 4 + r;    // = c*32 + q
                const float wgt = s_w[row >> 5][row & 31];
                const int cb = (nt3 * 16 + lrow) * 4;
                *(float*)(buf + row * 256 + LDS_SWZ(row, cb)) = acc3[mt][r] * wgt;
            }
        }
    }
    __syncthreads();

    // ---- final: sum 4 corner rows, fully-coalesced dwordx4 store ----
    {
        const int q  = tid >> 4;          // 0..31
        const int ch = (tid & 15) * 4;    // 0..60
        f32x4 sum = (f32x4){0.f, 0.f, 0.f, 0.f};
        #pragma unroll
        for (int c = 0; c < 4; ++c) {
            const int row = c * 32 + q;
            const f32x4 v = *(const f32x4*)(buf + row * 256 + LDS_SWZ(row, ch * 4));
            sum += v;
        }
        *(f32x4*)(out + ((size_t)b * 65536 + q0 + q) * 64 + ch) = sum;
    }
}

extern "C" void kernel_launch(void* const* d_in, const int* in_sizes, int n_in,
                              void* d_out, int out_size, void* d_ws, size_t ws_size,
                              hipStream_t stream) {
    const float* x  = (const float*)d_in[0];
    const float* W1 = (const float*)d_in[1];
    const float* b1 = (const float*)d_in[2];
    const float* W2 = (const float*)d_in[3];
    const float* b2 = (const float*)d_in[4];
    const float* W3 = (const float*)d_in[5];
    const float* b3 = (const float*)d_in[6];
    float* out = (float*)d_out;
    ushort* wp = (ushort*)d_ws;

    prep_weights<<<208, 64, 0, stream>>>(W1, W2, W3, wp);
    liif_mfma3_kernel<<<8192, 512, 0, stream>>>(x, b1, b2, b3, wp, out);
}

// Round 6
// 269.822 us; speedup vs baseline: 6.1637x; 1.7077x over previous
//
#include <hip/hip_runtime.h>

// LIIF local-ensemble upsampling — bf16 MFMA, corner-parallel, spill-free.
// WG = 256 threads (4 waves) = 16 queries x 4 corners = M=64 rows through
// MLP 66->256->256->64 once. Wave w owns 64x64 tile (N-quarter), acc[4][4].
// LDS: bufI 16K (inp str256, later pred f32) + bufH 32K (h1/h2 str512)
// = ~49.5KB -> 3 WG/CU. launch_bounds(256,3) => ~168 regs: 64 AGPR acc +
// ~104 arch VGPR -> no spill (round 4/5 spilled at the 64-arch split).
// 6 barriers per WG. Weights pre-swizzled to bf16 B-fragments in d_ws.

typedef __bf16 bf16x8 __attribute__((ext_vector_type(8)));
typedef float  f32x4  __attribute__((ext_vector_type(4)));

#define LDS_SWZ(row, kbyte) ((kbyte) ^ (((row) & 7) << 4))

// ws layout (ushort elements): W1p 48 frag-blocks, W2p 128, W3p 32 (1KB each)
#define WP1_U 0
#define WP2_U (48 * 512)
#define WP3_U (176 * 512)

// ---------------- weight prep: fp32 [K][N] -> bf16 B-fragments ----------------
// frag block: [ks][ntile][lane][8]  (lane l: k = ks*32+(l>>4)*8+j, n = nt*16+(l&15))
__global__ __launch_bounds__(64) void prep_weights(
    const float* __restrict__ W1, const float* __restrict__ W2,
    const float* __restrict__ W3, ushort* __restrict__ ws)
{
    const int blk = blockIdx.x;    // 0..207
    const int l   = threadIdx.x;   // 0..63
    const float* W; int Kreal, N, ks, nt; size_t off;
    if (blk < 48)       { W = W1; Kreal = 66;  N = 256; ks = blk >> 4;  nt = blk & 15; off = WP1_U + (size_t)blk * 512; }
    else if (blk < 176) { int b2 = blk - 48;  W = W2; Kreal = 256; N = 256; ks = b2 >> 4; nt = b2 & 15; off = WP2_U + (size_t)b2 * 512; }
    else                { int b3 = blk - 176; W = W3; Kreal = 256; N = 64;  ks = b3 >> 2; nt = b3 & 3;  off = WP3_U + (size_t)b3 * 512; }

    const int n = nt * 16 + (l & 15);
    ushort v[8];
    #pragma unroll
    for (int j = 0; j < 8; ++j) {
        const int k = ks * 32 + ((l >> 4) * 8) + j;
        const float f = (k < Kreal) ? W[(size_t)k * N + n] : 0.0f;
        v[j] = __builtin_bit_cast(ushort, (__bf16)f);
    }
    *(uint4*)(ws + off + (size_t)l * 8) = *(const uint4*)v;
}

// ---------------- K-loop: LDS(src rows 0..63) x Wp + bias -> acc ----------------
template<int KSTEPS, int SRC_STRIDE>
__device__ inline void compute_layer(const char* __restrict__ src,
                                     const ushort* __restrict__ wp,
                                     const float* __restrict__ bias,
                                     int lane, int nbase_t, f32x4 (&acc)[4][4])
{
    const int lrow = lane & 15;
    const int lk   = lane >> 4;
    #pragma unroll
    for (int nt = 0; nt < 4; ++nt) {
        const float bs = bias[(nbase_t + nt) * 16 + lrow];
        #pragma unroll
        for (int mt = 0; mt < 4; ++mt)
            acc[mt][nt] = (f32x4){bs, bs, bs, bs};
    }

    const ushort* wpl = wp + (((size_t)nbase_t) << 9) + (lane << 3);
    #pragma unroll 1
    for (int ks = 0; ks < KSTEPS; ++ks) {
        bf16x8 bb[4];
        #pragma unroll
        for (int nt = 0; nt < 4; ++nt)
            bb[nt] = *(const bf16x8*)(wpl + (((size_t)(ks * 16 + nt)) << 9));
        #pragma unroll
        for (int mt = 0; mt < 4; ++mt) {
            const int row   = mt * 16 + lrow;
            const int kbyte = ks * 64 + lk * 16;
            const bf16x8 a = *(const bf16x8*)(src + row * SRC_STRIDE + LDS_SWZ(row, kbyte));
            __builtin_amdgcn_s_setprio(1);
            #pragma unroll
            for (int nt = 0; nt < 4; ++nt)
                acc[mt][nt] = __builtin_amdgcn_mfma_f32_16x16x32_bf16(a, bb[nt], acc[mt][nt], 0, 0, 0);
            __builtin_amdgcn_s_setprio(0);
        }
    }
}

// ---------------- epilogue: relu(acc) -> bf16 LDS tile (stride 512B) ----------------
__device__ inline void store_hidden(char* __restrict__ dst, const f32x4 (&acc)[4][4],
                                    int lane, int nbase_t)
{
    const int lrow = lane & 15;
    const int lk   = lane >> 4;
    #pragma unroll
    for (int nt = 0; nt < 4; ++nt) {
        const int n  = (nbase_t + nt) * 16 + lrow;
        const int kbyte = 2 * n;
        #pragma unroll
        for (int mt = 0; mt < 4; ++mt) {
            #pragma unroll
            for (int r = 0; r < 4; ++r) {
                const int row = mt * 16 + lk * 4 + r;
                const float v = fmaxf(acc[mt][nt][r], 0.0f);
                *(ushort*)(dst + row * 512 + LDS_SWZ(row, kbyte)) = __builtin_bit_cast(ushort, (__bf16)v);
            }
        }
    }
}

// ---------------- main kernel ----------------
__global__ __launch_bounds__(256, 3) void liif_mfma4_kernel(
    const float* __restrict__ x,
    const float* __restrict__ b1f, const float* __restrict__ b2f, const float* __restrict__ b3f,
    const ushort* __restrict__ ws, float* __restrict__ out)
{
    __shared__ char bufI[16 * 1024];   // inp (64 rows, str256, swizzled) -> pred f32
    __shared__ char bufH[32 * 1024];   // h1/h2 (64 rows, str512, swizzled)
    __shared__ int   s_iy[4][16], s_ix[4][16];
    __shared__ float s_rely[4][16], s_relx[4][16], s_w[4][16];

    const int tid  = threadIdx.x;
    const int lane = tid & 63;
    const int wv   = tid >> 6;            // 0..3
    const int lrow = lane & 15;
    const int lk   = lane >> 4;

    const int bid0 = blockIdx.x;          // 0..16383
    const int bid  = (bid0 & 7) * 2048 + (bid0 >> 3);   // XCD-contiguous remap (bijective)
    const int b    = bid >> 12;           // batch 0..3
    const int q0   = (bid & 4095) << 4;   // 16 queries per WG

    const int nbase_t = wv * 4;           // N-quarter per wave (x16 cols)

    // ---- per-query geometry, all 4 corners ----
    if (tid < 16) {
        const int q  = q0 + tid;
        const int yq = q >> 8, xq = q & 255;
        const float cy  = -1.0f + (2.0f * yq + 1.0f) / 256.0f;
        const float cx  = -1.0f + (2.0f * xq + 1.0f) / 256.0f;
        const float lim = 1.0f - 1e-6f;
        float area[4];
        #pragma unroll
        for (int c = 0; c < 4; ++c) {
            const float vx = (c & 2) ? 1.0f : -1.0f;
            const float vy = (c & 1) ? 1.0f : -1.0f;
            float sy = cy + vx * (1.0f / 64.0f) + 1e-6f;
            float sx = cx + vy * (1.0f / 64.0f) + 1e-6f;
            sy = fminf(fmaxf(sy, -lim), lim);
            sx = fminf(fmaxf(sx, -lim), lim);
            int iy = (int)rintf(((sy + 1.0f) * 64.0f - 1.0f) * 0.5f);
            int ix = (int)rintf(((sx + 1.0f) * 64.0f - 1.0f) * 0.5f);
            iy = min(max(iy, 0), 63);
            ix = min(max(ix, 0), 63);
            const float fy = -1.0f + (2.0f * iy + 1.0f) / 64.0f;
            const float fx = -1.0f + (2.0f * ix + 1.0f) / 64.0f;
            const float ry = (cy - fy) * 64.0f;
            const float rx = (cx - fx) * 64.0f;
            s_iy[c][tid] = iy;   s_ix[c][tid] = ix;
            s_rely[c][tid] = ry; s_relx[c][tid] = rx;
            area[c] = fabsf(ry * rx) + 1e-9f;
        }
        const float tot = area[0] + area[1] + area[2] + area[3];
        #pragma unroll
        for (int c = 0; c < 4; ++c) s_w[c][tid] = area[3 - c] / tot;   // 0<->3, 1<->2 swap
    }
    __syncthreads();

    // ---- stage inp tile: row = c*16+q, 64 rows, str256, swizzled, K->96 ----
    {
        const int r = tid >> 2, p = tid & 3;    // 4 threads per row
        const int c = r >> 4, q = r & 15;
        const int iy = s_iy[c][q], ix = s_ix[c][q];
        const float* xb = x + (size_t)b * 262144 + iy * 64 + ix;
        #pragma unroll
        for (int half = 0; half < 2; ++half) {
            ushort tmp[8];
            #pragma unroll
            for (int j = 0; j < 8; ++j) {
                const float f = xb[(size_t)(p * 16 + half * 8 + j) * 4096];
                tmp[j] = __builtin_bit_cast(ushort, (__bf16)f);
            }
            const int kbyte = p * 32 + half * 16;
            *(uint4*)(bufI + r * 256 + LDS_SWZ(r, kbyte)) = *(const uint4*)tmp;
        }
        ushort pad[8] = {0, 0, 0, 0, 0, 0, 0, 0};
        if (p == 0) {
            pad[0] = __builtin_bit_cast(ushort, (__bf16)s_rely[c][q]);
            pad[1] = __builtin_bit_cast(ushort, (__bf16)s_relx[c][q]);
        }
        const int kbyte = 128 + p * 16;
        *(uint4*)(bufI + r * 256 + LDS_SWZ(r, kbyte)) = *(const uint4*)pad;
    }
    __syncthreads();

    f32x4 acc[4][4];

    // ---- layer 1: inp(bufI) -> h1(bufH); separate regions, no inner barrier ----
    compute_layer<3, 256>(bufI, ws + WP1_U, b1f, lane, nbase_t, acc);
    store_hidden(bufH, acc, lane, nbase_t);
    __syncthreads();

    // ---- layer 2: h1 -> h2 (in place in bufH, barrier between read & write) ----
    compute_layer<8, 512>(bufH, ws + WP2_U, b2f, lane, nbase_t, acc);
    __syncthreads();
    store_hidden(bufH, acc, lane, nbase_t);
    __syncthreads();

    // ---- layer 3: h2(bufH) -> pred(bufI, f32, weighted); regions disjoint ----
    {
        const int nt3 = wv;               // one 16-col tile of N=64
        const float bs = b3f[nt3 * 16 + lrow];
        f32x4 acc3[4];
        #pragma unroll
        for (int mt = 0; mt < 4; ++mt) acc3[mt] = (f32x4){bs, bs, bs, bs};

        const ushort* wp3 = ws + WP3_U + (lane << 3);
        #pragma unroll 1
        for (int ks = 0; ks < 8; ++ks) {
            const bf16x8 bb = *(const bf16x8*)(wp3 + (((size_t)(ks * 4 + nt3)) << 9));
            #pragma unroll
            for (int mt = 0; mt < 4; ++mt) {
                const int row   = mt * 16 + lrow;
                const int kbyte = ks * 64 + lk * 16;
                const bf16x8 a = *(const bf16x8*)(bufH + row * 512 + LDS_SWZ(row, kbyte));
                __builtin_amdgcn_s_setprio(1);
                acc3[mt] = __builtin_amdgcn_mfma_f32_16x16x32_bf16(a, bb, acc3[mt], 0, 0, 0);
                __builtin_amdgcn_s_setprio(0);
            }
        }
        #pragma unroll
        for (int mt = 0; mt < 4; ++mt) {
            #pragma unroll
            for (int r = 0; r < 4; ++r) {
                const int row = mt * 16 + lk * 4 + r;    // = c*16 + q
                const float wgt = s_w[row >> 4][row & 15];
                const int cb = (nt3 * 16 + lrow) * 4;
                *(float*)(bufI + row * 256 + LDS_SWZ(row, cb)) = acc3[mt][r] * wgt;
            }
        }
    }
    __syncthreads();

    // ---- final: sum 4 corner rows, fully-coalesced dwordx4 store ----
    {
        const int q  = tid >> 4;          // 0..15
        const int ch = (tid & 15) * 4;    // 0..60
        f32x4 sum = (f32x4){0.f, 0.f, 0.f, 0.f};
        #pragma unroll
        for (int c = 0; c < 4; ++c) {
            const int row = c * 16 + q;
            const f32x4 v = *(const f32x4*)(bufI + row * 256 + LDS_SWZ(row, ch * 4));
            sum += v;
        }
        *(f32x4*)(out + ((size_t)b * 65536 + q0 + q) * 64 + ch) = sum;
    }
}

extern "C" void kernel_launch(void* const* d_in, const int* in_sizes, int n_in,
                              void* d_out, int out_size, void* d_ws, size_t ws_size,
                              hipStream_t stream) {
    const float* x  = (const float*)d_in[0];
    const float* W1 = (const float*)d_in[1];
    const float* b1 = (const float*)d_in[2];
    const float* W2 = (const float*)d_in[3];
    const float* b2 = (const float*)d_in[4];
    const float* W3 = (const float*)d_in[5];
    const float* b3 = (const float*)d_in[6];
    float* out = (float*)d_out;
    ushort* wp = (ushort*)d_ws;

    prep_weights<<<208, 64, 0, stream>>>(W1, W2, W3, wp);
    liif_mfma4_kernel<<<16384, 256, 0, stream>>>(x, b1, b2, b3, wp, out);
}